// Round 10
// baseline (783.795 us; speedup 1.0000x reference)
//
#include <hip/hip_runtime.h>

#define K_DIM  512
#define C_DIM  4096
#define RB     128           // x-rows per workgroup
#define CT     512           // codes per tile
#define NCT    (C_DIM / CT)  // 8
#define NKS    4             // K-steps of 128 elems per ct sweep (32 phases total)
#define ROWB   512           // bytes per fp8 row
// LDS: Es dbuf 2x64KB at [0]; Xs dbuf 2x16KB at [131072]; 160 KB total

typedef __attribute__((ext_vector_type(4)))  float f32x4;
typedef __attribute__((ext_vector_type(16))) float f32x16;
typedef __attribute__((ext_vector_type(4)))  int   i32x4;
typedef __attribute__((ext_vector_type(8)))  int   i32x8;

__device__ __forceinline__ void load16(const void* g, void* s) {
    __builtin_amdgcn_global_load_lds(
        (const __attribute__((address_space(1))) unsigned int*)g,
        (__attribute__((address_space(3))) unsigned int*)s, 16, 0, 0);
}

// float -> OCP e4m3fn, RNE (values here are far from 448 so satfinite is trivial)
__device__ __forceinline__ unsigned int f32_to_e4m3(float f) {
    unsigned int u  = __float_as_uint(f);
    unsigned int s  = (u >> 24) & 0x80u;
    unsigned int au = u & 0x7FFFFFFFu;
    float a = __uint_as_float(au);
    if (a >= 0.015625f) {                                  // normal (>= 2^-6)
        unsigned int r = au + 0x7FFFFu + ((au >> 20) & 1u); // RNE to 3-bit mantissa
        int ef = (int)((r >> 23) & 0xFFu) - 127;
        unsigned int m = (r >> 20) & 7u;
        if (ef > 8) { ef = 8; m = 6; }                      // clamp to 448
        return s | ((unsigned int)(ef + 7) << 3) | m;
    } else {                                               // subnormal: quantum 2^-9
        int q = __float2int_rn(a * 512.0f);                // 0..8 (8 -> 2^-6 normal)
        return s | (unsigned int)q;
    }
}

// prepass: x -> X8 fp8 (in d_out), e -> E8 fp8 (in ws)
__global__ __launch_bounds__(256)
void convert_fp8(const float* __restrict__ x, const float* __restrict__ e,
                 unsigned char* __restrict__ X8, unsigned char* __restrict__ E8, int xblocks) {
    const long bid = blockIdx.x;
    const float* src; unsigned char* dst; long base;
    if (bid < xblocks) { src = x; dst = X8; base = (bid * 256 + threadIdx.x) * 8L; }
    else               { src = e; dst = E8; base = ((bid - xblocks) * 256 + threadIdx.x) * 8L; }
    float4 v0 = *(const float4*)(src + base);
    float4 v1 = *(const float4*)(src + base + 4);
    float f[8] = {v0.x, v0.y, v0.z, v0.w, v1.x, v1.y, v1.z, v1.w};
    unsigned int lo = 0, hi = 0;
#pragma unroll
    for (int j = 0; j < 4; ++j) lo |= f32_to_e4m3(f[j])     << (8 * j);
#pragma unroll
    for (int j = 0; j < 4; ++j) hi |= f32_to_e4m3(f[4 + j]) << (8 * j);
    *(uint2*)(dst + base) = make_uint2(lo, hi);
}

// MX-fp8 proxy GEMM (swapped operands: MFMA A = codes, B = x-rows) + top-8 candidates.
// R7 barrier structure; K=128 elems per phase; 8-chunk XOR swizzle (both-sides, rule #21).
// mfma_scale_f32_32x32x64_f8f6f4 with unit scales (0x7F per block).
__global__ __launch_bounds__(512, 2)
void vq_gemm(const unsigned char* __restrict__ X8,
             const unsigned char* __restrict__ E8,
             int* __restrict__ cand) {
    extern __shared__ unsigned char lds[];

    const int tid = threadIdx.x;
    const int l   = tid & 63;
    const int wid = tid >> 6;     // 0..7
    const int wc  = wid & 3;      // code group: codes wc*128..+128 within tile
    const int wr  = wid >> 2;     // row group: rows wr*64..+64
    const long row0 = (long)blockIdx.x * RB;
    const int kg = l >> 5;        // K half-group (32-elem block index within K64)
    const int lm = l & 31;        // M/N index within 32-tile

    // rows are 128 B slices in LDS; granule = chunk ^ (row&7) -> perfect 8-row bijection
    auto stage = [&](int buf, int ct, int t) {
#pragma unroll
        for (int i = 0; i < 2; ++i) {   // X slice: 128 rows x 128 B
            int row = wid * 16 + i * 8 + (l >> 3);
            int c   = l & 7;
            const unsigned char* g = X8
                + (row0 + row) * ROWB + t * 128 + ((c ^ (row & 7)) << 4);
            load16(g, lds + 131072 + buf * 16384 + wid * 2048 + i * 1024);
        }
#pragma unroll
        for (int h = 0; h < 8; ++h) {   // E slice: 512 rows x 128 B
            int row = wid * 64 + h * 8 + (l >> 3);
            int c   = l & 7;
            const unsigned char* g = E8
                + (long)(ct * CT + row) * ROWB + t * 128 + ((c ^ (row & 7)) << 4);
            load16(g, lds + buf * 65536 + wid * 8192 + h * 1024);
        }
    };

    // per-lane (slot) running top-4 per xn tile, global across ct
    float q0[2], q1[2], q2[2], q3[2]; int i0[2], i1[2], i2[2], i3[2];
#pragma unroll
    for (int xn = 0; xn < 2; ++xn) {
        q0[xn] = q1[xn] = q2[xn] = q3[xn] = -3.0e38f;
        i0[xn] = i1[xn] = i2[xn] = i3[xn] = 0;
    }

    f32x16 acc[4][2];
    int cur = 0;
    stage(0, 0, 0);
    __syncthreads();

    for (int ct = 0; ct < NCT; ++ct) {
#pragma unroll
        for (int cm = 0; cm < 4; ++cm)
#pragma unroll
            for (int xn = 0; xn < 2; ++xn)
#pragma unroll
                for (int r = 0; r < 16; ++r) acc[cm][xn][r] = 0.0f;

        for (int t = 0; t < NKS; ++t) {
            if (t + 1 < NKS)          stage(cur ^ 1, ct, t + 1);
            else if (ct + 1 < NCT)    stage(cur ^ 1, ct + 1, 0);

            const unsigned char* Es = lds + cur * 65536;
            const unsigned char* Xs = lds + 131072 + cur * 16384;

            // 2 K64 sub-steps; lane's 32-byte k-block = bytes kb*64 + kg*32 .. +32
#pragma unroll
            for (int kb = 0; kb < 2; ++kb) {
                const int u0 = kb * 4 + kg * 2;   // 16B-chunk pair within 128 B slice
                i32x8 afr[4], bfr[2];
#pragma unroll
                for (int cm = 0; cm < 4; ++cm) {
                    int R  = wc * 128 + cm * 32 + lm;
                    const unsigned char* base = Es + R * 128;
                    i32x4 lo = *(const i32x4*)(base + (((u0)     ^ (R & 7)) << 4));
                    i32x4 hi = *(const i32x4*)(base + (((u0 + 1) ^ (R & 7)) << 4));
                    afr[cm][0] = lo[0]; afr[cm][1] = lo[1]; afr[cm][2] = lo[2]; afr[cm][3] = lo[3];
                    afr[cm][4] = hi[0]; afr[cm][5] = hi[1]; afr[cm][6] = hi[2]; afr[cm][7] = hi[3];
                }
#pragma unroll
                for (int xn = 0; xn < 2; ++xn) {
                    int R  = wr * 64 + xn * 32 + lm;
                    const unsigned char* base = Xs + R * 128;
                    i32x4 lo = *(const i32x4*)(base + (((u0)     ^ (R & 7)) << 4));
                    i32x4 hi = *(const i32x4*)(base + (((u0 + 1) ^ (R & 7)) << 4));
                    bfr[xn][0] = lo[0]; bfr[xn][1] = lo[1]; bfr[xn][2] = lo[2]; bfr[xn][3] = lo[3];
                    bfr[xn][4] = hi[0]; bfr[xn][5] = hi[1]; bfr[xn][6] = hi[2]; bfr[xn][7] = hi[3];
                }
                __builtin_amdgcn_s_setprio(1);
#pragma unroll
                for (int cm = 0; cm < 4; ++cm)
#pragma unroll
                    for (int xn = 0; xn < 2; ++xn)
                        acc[cm][xn] = __builtin_amdgcn_mfma_scale_f32_32x32x64_f8f6f4(
                            afr[cm], bfr[xn], acc[cm][xn],
                            0, 0,                       // cbsz = fp8(e4m3), blgp = fp8(e4m3)
                            0, 0x7F7F7F7F,              // A scale: opsel 0, E8M0 1.0 all bytes
                            0, 0x7F7F7F7F);             // B scale: opsel 0, E8M0 1.0 all bytes
                __builtin_amdgcn_s_setprio(0);
            }

            __syncthreads();
            cur ^= 1;
        }

        // insert this tile's values into per-lane top-4.
        // C/D layout (32x32, shape-determined): col(=x-row)=l&31, code row=(r&3)+8*(r>>2)+4*kg
#pragma unroll
        for (int xn = 0; xn < 2; ++xn) {
#pragma unroll
            for (int cm = 0; cm < 4; ++cm) {
                const int cbase = ct * CT + wc * 128 + cm * 32 + 4 * kg;
#pragma unroll
                for (int r = 0; r < 16; ++r) {
                    float v = acc[cm][xn][r];
                    int  cc = cbase + (r & 3) + 8 * (r >> 2);
                    bool b0 = v > q0[xn], b1 = v > q1[xn], b2 = v > q2[xn], b3 = v > q3[xn];
                    q3[xn] = b3 ? (b2 ? q2[xn] : v)  : q3[xn];
                    i3[xn] = b3 ? (b2 ? i2[xn] : cc) : i3[xn];
                    q2[xn] = b2 ? (b1 ? q1[xn] : v)  : q2[xn];
                    i2[xn] = b2 ? (b1 ? i1[xn] : cc) : i2[xn];
                    q1[xn] = b1 ? (b0 ? q0[xn] : v)  : q1[xn];
                    i1[xn] = b1 ? (b0 ? i0[xn] : cc) : i1[xn];
                    q0[xn] = b0 ? v  : q0[xn];
                    i0[xn] = b0 ? cc : i0[xn];
                }
            }
        }
    }

    // merge: 8 slots x 4 = 32 candidates/row via LDS -> top-8 -> cand[]
    __syncthreads();
    float2* cl = (float2*)lds;            // [128 rows][32 slots]
    const int slot = wc * 2 + kg;         // 0..7 per x-row
#pragma unroll
    for (int xn = 0; xn < 2; ++xn) {
        int rl = wr * 64 + xn * 32 + lm;
        cl[rl * 32 + slot * 4 + 0] = make_float2(q0[xn], __int_as_float(i0[xn]));
        cl[rl * 32 + slot * 4 + 1] = make_float2(q1[xn], __int_as_float(i1[xn]));
        cl[rl * 32 + slot * 4 + 2] = make_float2(q2[xn], __int_as_float(i2[xn]));
        cl[rl * 32 + slot * 4 + 3] = make_float2(q3[xn], __int_as_float(i3[xn]));
    }
    __syncthreads();

    if (tid < RB) {
        float tv[8]; int tu[8];
#pragma unroll
        for (int d = 0; d < 8; ++d) { tv[d] = -3.0e38f; tu[d] = 0; }
        for (int k = 0; k < 32; ++k) {
            float2 p = cl[tid * 32 + k];
            float v = p.x; int cc = __float_as_int(p.y);
            bool b[8];
#pragma unroll
            for (int d = 0; d < 8; ++d) b[d] = v > tv[d];
#pragma unroll
            for (int d = 7; d > 0; --d) {
                tv[d] = b[d] ? (b[d - 1] ? tv[d - 1] : v)  : tv[d];
                tu[d] = b[d] ? (b[d - 1] ? tu[d - 1] : cc) : tu[d];
            }
            tv[0] = b[0] ? v : tv[0];
            tu[0] = b[0] ? cc : tu[0];
        }
        int4 w0, w1;
        w0.x = tu[0]; w0.y = tu[1]; w0.z = tu[2]; w0.w = tu[3];
        w1.x = tu[4]; w1.y = tu[5]; w1.z = tu[6]; w1.w = tu[7];
        *(int4*)(cand + (row0 + tid) * 8)     = w0;
        *(int4*)(cand + (row0 + tid) * 8 + 4) = w1;
    }
}

// exact fp32 rerank of the 8 candidates + gather e[winner] -> out
__global__ __launch_bounds__(256)
void rerank_gather(const float* __restrict__ x, const float* __restrict__ e,
                   const int* __restrict__ cand, float* __restrict__ out) {
    const int tid = threadIdx.x;
    const int l   = tid & 63;
    const int w   = tid >> 6;
    const long row = (long)blockIdx.x * 4 + w;

    const float* xr = x + row * K_DIM + l * 8;
    f32x4 xv0 = *(const f32x4*)(xr);
    f32x4 xv1 = *(const f32x4*)(xr + 4);

    float d[8]; int c[8];
#pragma unroll
    for (int i = 0; i < 8; ++i) {
        c[i] = cand[row * 8 + i];
        const float* er = e + (long)c[i] * K_DIM + l * 8;
        f32x4 ev0 = *(const f32x4*)(er);
        f32x4 ev1 = *(const f32x4*)(er + 4);
        float s = 0.0f;
        s = fmaf(xv0[0], ev0[0], s); s = fmaf(xv0[1], ev0[1], s);
        s = fmaf(xv0[2], ev0[2], s); s = fmaf(xv0[3], ev0[3], s);
        s = fmaf(xv1[0], ev1[0], s); s = fmaf(xv1[1], ev1[1], s);
        s = fmaf(xv1[2], ev1[2], s); s = fmaf(xv1[3], ev1[3], s);
        d[i] = s;
    }
#pragma unroll
    for (int m = 1; m < 64; m <<= 1)
#pragma unroll
        for (int i = 0; i < 8; ++i) d[i] += __shfl_xor(d[i], m);

    float bv = d[0]; int bc = c[0];
#pragma unroll
    for (int i = 1; i < 8; ++i)
        if (d[i] > bv || (d[i] == bv && c[i] < bc)) { bv = d[i]; bc = c[i]; }

    const float4* src = (const float4*)(e + (long)bc * K_DIM) + l * 2;
    float4*       dst = (float4*)(out + row * K_DIM) + l * 2;
    dst[0] = src[0];
    dst[1] = src[1];
}

extern "C" void kernel_launch(void* const* d_in, const int* in_sizes, int n_in,
                              void* d_out, int out_size, void* d_ws, size_t ws_size,
                              hipStream_t stream) {
    const float* x = (const float*)d_in[0];   // [M, 512] fp32
    const float* e = (const float*)d_in[1];   // [4096, 512] fp32
    float* out = (float*)d_out;

    const int M  = in_sizes[0] / K_DIM;       // 32768
    const int Ce = in_sizes[1] / K_DIM;       // 4096

    unsigned char* X8 = (unsigned char*)d_out;                 // 16 MiB fp8, dead before out written
    unsigned char* E8 = (unsigned char*)d_ws;                  // 2 MiB fp8
    int* cand = (int*)((char*)d_ws + (size_t)Ce * K_DIM);      // M*8 ints (1 MiB)

    (void)hipFuncSetAttribute((const void*)vq_gemm,
                              hipFuncAttributeMaxDynamicSharedMemorySize, 163840);

    const int xb = M / 4, eb = Ce / 4;        // 8 elems/thread, 256 thr/block
    convert_fp8<<<xb + eb, 256, 0, stream>>>(x, e, X8, E8, xb);
    vq_gemm<<<M / RB, 512, 163840, stream>>>(X8, E8, cand);
    rerank_gather<<<M / 4, 256, 0, stream>>>(x, e, cand, out);
}

// Round 11
// 631.066 us; speedup vs baseline: 1.2420x; 1.2420x over previous
//
#include <hip/hip_runtime.h>

#define K_DIM  512
#define C_DIM  4096
#define RB     128           // x-rows per workgroup
#define CT     256           // codes per tile
#define NCT    (C_DIM / CT)  // 16
#define NKS    4             // K-steps of 128 elems per ct sweep (64 phases total)
#define ROWB   512           // bytes per fp8 row
// LDS: Es dbuf 2x32KB at [0]; Xs dbuf 2x16KB at [65536]; 96 KB total

typedef __attribute__((ext_vector_type(4)))  float f32x4;
typedef __attribute__((ext_vector_type(16))) float f32x16;
typedef __attribute__((ext_vector_type(4)))  int   i32x4;
typedef __attribute__((ext_vector_type(8)))  int   i32x8;

__device__ __forceinline__ void load16(const void* g, void* s) {
    __builtin_amdgcn_global_load_lds(
        (const __attribute__((address_space(1))) unsigned int*)g,
        (__attribute__((address_space(3))) unsigned int*)s, 16, 0, 0);
}

// float -> OCP e4m3fn, RNE
__device__ __forceinline__ unsigned int f32_to_e4m3(float f) {
    unsigned int u  = __float_as_uint(f);
    unsigned int s  = (u >> 24) & 0x80u;
    unsigned int au = u & 0x7FFFFFFFu;
    float a = __uint_as_float(au);
    if (a >= 0.015625f) {                                   // normal (>= 2^-6)
        unsigned int r = au + 0x7FFFFu + ((au >> 20) & 1u); // RNE to 3-bit mantissa
        int ef = (int)((r >> 23) & 0xFFu) - 127;
        unsigned int m = (r >> 20) & 7u;
        if (ef > 8) { ef = 8; m = 6; }                      // clamp to 448
        return s | ((unsigned int)(ef + 7) << 3) | m;
    } else {                                                // subnormal: quantum 2^-9
        int q = __float2int_rn(a * 512.0f);
        return s | (unsigned int)q;
    }
}

// prepass: x -> X8 fp8 (in d_out), e -> E8 fp8 (in ws)
__global__ __launch_bounds__(256)
void convert_fp8(const float* __restrict__ x, const float* __restrict__ e,
                 unsigned char* __restrict__ X8, unsigned char* __restrict__ E8, int xblocks) {
    const long bid = blockIdx.x;
    const float* src; unsigned char* dst; long base;
    if (bid < xblocks) { src = x; dst = X8; base = (bid * 256 + threadIdx.x) * 8L; }
    else               { src = e; dst = E8; base = ((bid - xblocks) * 256 + threadIdx.x) * 8L; }
    float4 v0 = *(const float4*)(src + base);
    float4 v1 = *(const float4*)(src + base + 4);
    float f[8] = {v0.x, v0.y, v0.z, v0.w, v1.x, v1.y, v1.z, v1.w};
    unsigned int lo = 0, hi = 0;
#pragma unroll
    for (int j = 0; j < 4; ++j) lo |= f32_to_e4m3(f[j])     << (8 * j);
#pragma unroll
    for (int j = 0; j < 4; ++j) hi |= f32_to_e4m3(f[4 + j]) << (8 * j);
    *(uint2*)(dst + base) = make_uint2(lo, hi);
}

// MX-fp8 proxy GEMM (swapped operands: MFMA A = codes, B = x-rows) + top-8 candidates.
// R7 barrier structure; wave tile 64 codes x 64 rows (acc[2][2], spill-proof);
// K=128 elems per phase; 8-chunk XOR swizzle both-sides (rule #21); unit MX scales.
__global__ __launch_bounds__(512, 1)
void vq_gemm(const unsigned char* __restrict__ X8,
             const unsigned char* __restrict__ E8,
             int* __restrict__ cand) {
    extern __shared__ unsigned char lds[];

    const int tid = threadIdx.x;
    const int l   = tid & 63;
    const int wid = tid >> 6;     // 0..7
    const int wc  = wid & 3;      // code group: codes wc*64..+64 within tile
    const int wr  = wid >> 2;     // row group: rows wr*64..+64
    const long row0 = (long)blockIdx.x * RB;
    const int kg = l >> 5;        // K half-group (32-elem block within K64)
    const int lm = l & 31;        // M/N index within 32-tile

    // rows are 128 B slices in LDS; granule = chunk ^ (row&7) -> perfect 8-row bijection
    auto stage = [&](int buf, int ct, int t) {
#pragma unroll
        for (int i = 0; i < 2; ++i) {   // X slice: 128 rows x 128 B
            int row = wid * 16 + i * 8 + (l >> 3);
            int c   = l & 7;
            const unsigned char* g = X8
                + (row0 + row) * ROWB + t * 128 + ((c ^ (row & 7)) << 4);
            load16(g, lds + 65536 + buf * 16384 + wid * 2048 + i * 1024);
        }
#pragma unroll
        for (int h = 0; h < 4; ++h) {   // E slice: 256 rows x 128 B
            int row = wid * 32 + h * 8 + (l >> 3);
            int c   = l & 7;
            const unsigned char* g = E8
                + (long)(ct * CT + row) * ROWB + t * 128 + ((c ^ (row & 7)) << 4);
            load16(g, lds + buf * 32768 + wid * 4096 + h * 1024);
        }
    };

    // per-lane (slot) running top-4 per xn tile, global across ct
    float q0[2], q1[2], q2[2], q3[2]; int i0[2], i1[2], i2[2], i3[2];
#pragma unroll
    for (int xn = 0; xn < 2; ++xn) {
        q0[xn] = q1[xn] = q2[xn] = q3[xn] = -3.0e38f;
        i0[xn] = i1[xn] = i2[xn] = i3[xn] = 0;
    }

    f32x16 acc[2][2];
    int cur = 0;
    stage(0, 0, 0);
    __syncthreads();

    for (int ct = 0; ct < NCT; ++ct) {
#pragma unroll
        for (int cm = 0; cm < 2; ++cm)
#pragma unroll
            for (int xn = 0; xn < 2; ++xn)
#pragma unroll
                for (int r = 0; r < 16; ++r) acc[cm][xn][r] = 0.0f;

        for (int t = 0; t < NKS; ++t) {
            if (t + 1 < NKS)          stage(cur ^ 1, ct, t + 1);
            else if (ct + 1 < NCT)    stage(cur ^ 1, ct + 1, 0);

            const unsigned char* Es = lds + cur * 32768;
            const unsigned char* Xs = lds + 65536 + cur * 16384;

            // 2 K64 sub-steps; lane's 32-byte k-block = bytes kb*64 + kg*32 .. +32
#pragma unroll
            for (int kb = 0; kb < 2; ++kb) {
                const int u0 = kb * 4 + kg * 2;   // 16B-chunk pair within 128 B slice
                i32x8 afr[2], bfr[2];
#pragma unroll
                for (int cm = 0; cm < 2; ++cm) {
                    int R  = wc * 64 + cm * 32 + lm;
                    const unsigned char* base = Es + R * 128;
                    i32x4 lo = *(const i32x4*)(base + (((u0)     ^ (R & 7)) << 4));
                    i32x4 hi = *(const i32x4*)(base + (((u0 + 1) ^ (R & 7)) << 4));
                    afr[cm][0] = lo[0]; afr[cm][1] = lo[1]; afr[cm][2] = lo[2]; afr[cm][3] = lo[3];
                    afr[cm][4] = hi[0]; afr[cm][5] = hi[1]; afr[cm][6] = hi[2]; afr[cm][7] = hi[3];
                }
#pragma unroll
                for (int xn = 0; xn < 2; ++xn) {
                    int R  = wr * 64 + xn * 32 + lm;
                    const unsigned char* base = Xs + R * 128;
                    i32x4 lo = *(const i32x4*)(base + (((u0)     ^ (R & 7)) << 4));
                    i32x4 hi = *(const i32x4*)(base + (((u0 + 1) ^ (R & 7)) << 4));
                    bfr[xn][0] = lo[0]; bfr[xn][1] = lo[1]; bfr[xn][2] = lo[2]; bfr[xn][3] = lo[3];
                    bfr[xn][4] = hi[0]; bfr[xn][5] = hi[1]; bfr[xn][6] = hi[2]; bfr[xn][7] = hi[3];
                }
                __builtin_amdgcn_s_setprio(1);
#pragma unroll
                for (int cm = 0; cm < 2; ++cm)
#pragma unroll
                    for (int xn = 0; xn < 2; ++xn)
                        acc[cm][xn] = __builtin_amdgcn_mfma_scale_f32_32x32x64_f8f6f4(
                            afr[cm], bfr[xn], acc[cm][xn],
                            0, 0,                       // cbsz = fp8(e4m3), blgp = fp8(e4m3)
                            0, 0x7F7F7F7F,              // A scale: E8M0 1.0 all bytes
                            0, 0x7F7F7F7F);             // B scale: E8M0 1.0 all bytes
                __builtin_amdgcn_s_setprio(0);
            }

            __syncthreads();
            cur ^= 1;
        }

        // insert this tile's values into per-lane top-4.
        // C/D layout (32x32, shape-determined): col(=x-row)=l&31, code row=(r&3)+8*(r>>2)+4*kg
#pragma unroll
        for (int xn = 0; xn < 2; ++xn) {
#pragma unroll
            for (int cm = 0; cm < 2; ++cm) {
                const int cbase = ct * CT + wc * 64 + cm * 32 + 4 * kg;
#pragma unroll
                for (int r = 0; r < 16; ++r) {
                    float v = acc[cm][xn][r];
                    int  cc = cbase + (r & 3) + 8 * (r >> 2);
                    bool b0 = v > q0[xn], b1 = v > q1[xn], b2 = v > q2[xn], b3 = v > q3[xn];
                    q3[xn] = b3 ? (b2 ? q2[xn] : v)  : q3[xn];
                    i3[xn] = b3 ? (b2 ? i2[xn] : cc) : i3[xn];
                    q2[xn] = b2 ? (b1 ? q1[xn] : v)  : q2[xn];
                    i2[xn] = b2 ? (b1 ? i1[xn] : cc) : i2[xn];
                    q1[xn] = b1 ? (b0 ? q0[xn] : v)  : q1[xn];
                    i1[xn] = b1 ? (b0 ? i0[xn] : cc) : i1[xn];
                    q0[xn] = b0 ? v  : q0[xn];
                    i0[xn] = b0 ? cc : i0[xn];
                }
            }
        }
    }

    // merge: 8 slots x 4 = 32 candidates/row via LDS -> top-8 -> cand[]
    __syncthreads();
    float2* cl = (float2*)lds;            // [128 rows][32 slots]
    const int slot = wc * 2 + kg;         // 0..7 per x-row
#pragma unroll
    for (int xn = 0; xn < 2; ++xn) {
        int rl = wr * 64 + xn * 32 + lm;
        cl[rl * 32 + slot * 4 + 0] = make_float2(q0[xn], __int_as_float(i0[xn]));
        cl[rl * 32 + slot * 4 + 1] = make_float2(q1[xn], __int_as_float(i1[xn]));
        cl[rl * 32 + slot * 4 + 2] = make_float2(q2[xn], __int_as_float(i2[xn]));
        cl[rl * 32 + slot * 4 + 3] = make_float2(q3[xn], __int_as_float(i3[xn]));
    }
    __syncthreads();

    if (tid < RB) {
        float tv[8]; int tu[8];
#pragma unroll
        for (int d = 0; d < 8; ++d) { tv[d] = -3.0e38f; tu[d] = 0; }
        for (int k = 0; k < 32; ++k) {
            float2 p = cl[tid * 32 + k];
            float v = p.x; int cc = __float_as_int(p.y);
            bool b[8];
#pragma unroll
            for (int d = 0; d < 8; ++d) b[d] = v > tv[d];
#pragma unroll
            for (int d = 7; d > 0; --d) {
                tv[d] = b[d] ? (b[d - 1] ? tv[d - 1] : v)  : tv[d];
                tu[d] = b[d] ? (b[d - 1] ? tu[d - 1] : cc) : tu[d];
            }
            tv[0] = b[0] ? v : tv[0];
            tu[0] = b[0] ? cc : tu[0];
        }
        int4 w0, w1;
        w0.x = tu[0]; w0.y = tu[1]; w0.z = tu[2]; w0.w = tu[3];
        w1.x = tu[4]; w1.y = tu[5]; w1.z = tu[6]; w1.w = tu[7];
        *(int4*)(cand + (row0 + tid) * 8)     = w0;
        *(int4*)(cand + (row0 + tid) * 8 + 4) = w1;
    }
}

// exact fp32 rerank of the 8 candidates + gather e[winner] -> out
__global__ __launch_bounds__(256)
void rerank_gather(const float* __restrict__ x, const float* __restrict__ e,
                   const int* __restrict__ cand, float* __restrict__ out) {
    const int tid = threadIdx.x;
    const int l   = tid & 63;
    const int w   = tid >> 6;
    const long row = (long)blockIdx.x * 4 + w;

    const float* xr = x + row * K_DIM + l * 8;
    f32x4 xv0 = *(const f32x4*)(xr);
    f32x4 xv1 = *(const f32x4*)(xr + 4);

    float d[8]; int c[8];
#pragma unroll
    for (int i = 0; i < 8; ++i) {
        c[i] = cand[row * 8 + i];
        const float* er = e + (long)c[i] * K_DIM + l * 8;
        f32x4 ev0 = *(const f32x4*)(er);
        f32x4 ev1 = *(const f32x4*)(er + 4);
        float s = 0.0f;
        s = fmaf(xv0[0], ev0[0], s); s = fmaf(xv0[1], ev0[1], s);
        s = fmaf(xv0[2], ev0[2], s); s = fmaf(xv0[3], ev0[3], s);
        s = fmaf(xv1[0], ev1[0], s); s = fmaf(xv1[1], ev1[1], s);
        s = fmaf(xv1[2], ev1[2], s); s = fmaf(xv1[3], ev1[3], s);
        d[i] = s;
    }
#pragma unroll
    for (int m = 1; m < 64; m <<= 1)
#pragma unroll
        for (int i = 0; i < 8; ++i) d[i] += __shfl_xor(d[i], m);

    float bv = d[0]; int bc = c[0];
#pragma unroll
    for (int i = 1; i < 8; ++i)
        if (d[i] > bv || (d[i] == bv && c[i] < bc)) { bv = d[i]; bc = c[i]; }

    const float4* src = (const float4*)(e + (long)bc * K_DIM) + l * 2;
    float4*       dst = (float4*)(out + row * K_DIM) + l * 2;
    dst[0] = src[0];
    dst[1] = src[1];
}

extern "C" void kernel_launch(void* const* d_in, const int* in_sizes, int n_in,
                              void* d_out, int out_size, void* d_ws, size_t ws_size,
                              hipStream_t stream) {
    const float* x = (const float*)d_in[0];   // [M, 512] fp32
    const float* e = (const float*)d_in[1];   // [4096, 512] fp32
    float* out = (float*)d_out;

    const int M  = in_sizes[0] / K_DIM;       // 32768
    const int Ce = in_sizes[1] / K_DIM;       // 4096

    unsigned char* X8 = (unsigned char*)d_out;                 // 16 MiB fp8, dead before out written
    unsigned char* E8 = (unsigned char*)d_ws;                  // 2 MiB fp8
    int* cand = (int*)((char*)d_ws + (size_t)Ce * K_DIM);      // M*8 ints (1 MiB)

    (void)hipFuncSetAttribute((const void*)vq_gemm,
                              hipFuncAttributeMaxDynamicSharedMemorySize, 98304);

    const int xb = M / 4, eb = Ce / 4;        // 8 elems/thread, 256 thr/block
    convert_fp8<<<xb + eb, 256, 0, stream>>>(x, e, X8, E8, xb);
    vq_gemm<<<M / RB, 512, 98304, stream>>>(X8, E8, cand);
    rerank_gather<<<M / 4, 256, 0, stream>>>(x, e, cand, out);
}

// Round 13
// 224.296 us; speedup vs baseline: 3.4945x; 2.8135x over previous
//
#include <hip/hip_runtime.h>

#define K_DIM  512
#define C_DIM  4096
#define RB     128           // x-rows per workgroup
#define CT     512           // codes per tile
#define NCT    (C_DIM / CT)  // 8
#define NKS    8             // K-steps of 64 per ct sweep
#define ROWB   1024          // bytes per fp16 row (512 * 2)
// LDS: Es dbuf 2x64KB at [0]; Xs dbuf 2x16KB at [131072]; 160 KB total

typedef __attribute__((ext_vector_type(4)))  float    f32x4;
typedef __attribute__((ext_vector_type(16))) float    f32x16;
typedef _Float16 __attribute__((ext_vector_type(8)))  f16x8;

__device__ __forceinline__ void load16(const void* g, void* s) {
    __builtin_amdgcn_global_load_lds(
        (const __attribute__((address_space(1))) unsigned int*)g,
        (__attribute__((address_space(3))) unsigned int*)s, 16, 0, 0);
}

// prepass: x -> X1 fp16 (in d_out), e -> E1 fp16 (in ws)
__global__ __launch_bounds__(256)
void convert_f16(const float* __restrict__ x, const float* __restrict__ e,
                 _Float16* __restrict__ X1, _Float16* __restrict__ E1, int xblocks) {
    const long bid = blockIdx.x;
    const float* src; _Float16* dst; long base;
    if (bid < xblocks) { src = x; dst = X1; base = (bid * 256 + threadIdx.x) * 8L; }
    else               { src = e; dst = E1; base = ((bid - xblocks) * 256 + threadIdx.x) * 8L; }
    float4 v0 = *(const float4*)(src + base);
    float4 v1 = *(const float4*)(src + base + 4);
    f16x8 h;
    h[0] = (_Float16)v0.x; h[1] = (_Float16)v0.y; h[2] = (_Float16)v0.z; h[3] = (_Float16)v0.w;
    h[4] = (_Float16)v1.x; h[5] = (_Float16)v1.y; h[6] = (_Float16)v1.z; h[7] = (_Float16)v1.w;
    *(f16x8*)(dst + base) = h;
}

// fp16 proxy GEMM (swapped operands: MFMA A = codes, B = x-rows) + top-4 candidates.
// Proven 2-phase barrier structure; K=64 per phase (64 phases); 8-chunk XOR swizzle.
__global__ __launch_bounds__(512, 2)
void vq_gemm(const _Float16* __restrict__ X1,
             const _Float16* __restrict__ E1,
             int* __restrict__ cand) {
    extern __shared__ unsigned char lds[];

    const int tid = threadIdx.x;
    const int l   = tid & 63;
    const int wid = tid >> 6;     // 0..7
    const int wc  = wid & 3;      // code group: codes wc*128..+128 within tile
    const int wr  = wid >> 2;     // row group: rows wr*64..+64
    const long row0 = (long)blockIdx.x * RB;

    // rows are 128 B slices in LDS; granule = (chunk ^ (row&7)) -> perfect 8-row bijection.
    // Pre-swizzled global source + same XOR on reads (both-sides, rule #21).
    auto stage = [&](int buf, int ct, int t) {
#pragma unroll
        for (int i = 0; i < 2; ++i) {   // X slice: 128 rows x 128 B
            int row = wid * 16 + i * 8 + (l >> 3);
            int c   = l & 7;
            const unsigned char* g = (const unsigned char*)X1
                + (row0 + row) * ROWB + t * 128 + ((c ^ (row & 7)) << 4);
            load16(g, lds + 131072 + buf * 16384 + wid * 2048 + i * 1024);
        }
#pragma unroll
        for (int h = 0; h < 8; ++h) {   // E slice: 512 rows x 128 B
            int row = wid * 64 + h * 8 + (l >> 3);
            int c   = l & 7;
            const unsigned char* g = (const unsigned char*)E1
                + (long)(ct * CT + row) * ROWB + t * 128 + ((c ^ (row & 7)) << 4);
            load16(g, lds + buf * 65536 + wid * 8192 + h * 1024);
        }
    };

    // per-lane running top-2 per xn tile
    float q0[2], q1[2]; int i0[2], i1[2];
#pragma unroll
    for (int xn = 0; xn < 2; ++xn) { q0[xn] = -3.0e38f; q1[xn] = -3.0e38f; i0[xn] = 0; i1[xn] = 0; }

    f32x16 acc[4][2];
    int cur = 0;
    stage(0, 0, 0);
    __syncthreads();

    const int kg = l >> 5;        // K half-group for A/B frags
    const int lm = l & 31;        // M/N index within 32-tile

    for (int ct = 0; ct < NCT; ++ct) {
#pragma unroll
        for (int cm = 0; cm < 4; ++cm)
#pragma unroll
            for (int xn = 0; xn < 2; ++xn)
#pragma unroll
                for (int r = 0; r < 16; ++r) acc[cm][xn][r] = 0.0f;

        for (int t = 0; t < NKS; ++t) {
            if (t + 1 < NKS)          stage(cur ^ 1, ct, t + 1);
            else if (ct + 1 < NCT)    stage(cur ^ 1, ct + 1, 0);

            const unsigned char* Es = lds + cur * 65536;
            const unsigned char* Xs = lds + 131072 + cur * 16384;

            // 4 K16 sub-steps; frag chunk index = ks*2 + kg within the 128 B row slice
#pragma unroll
            for (int ks = 0; ks < 4; ++ks) {
                const int gk = ks * 2 + kg;
                f16x8 afr[4], bfr[2];
#pragma unroll
                for (int cm = 0; cm < 4; ++cm) {
                    int row = wc * 128 + cm * 32 + lm;
                    afr[cm] = *(const f16x8*)(Es + row * 128 + ((gk ^ (row & 7)) << 4));
                }
#pragma unroll
                for (int xn = 0; xn < 2; ++xn) {
                    int row = wr * 64 + xn * 32 + lm;
                    bfr[xn] = *(const f16x8*)(Xs + row * 128 + ((gk ^ (row & 7)) << 4));
                }
                __builtin_amdgcn_s_setprio(1);
#pragma unroll
                for (int cm = 0; cm < 4; ++cm)
#pragma unroll
                    for (int xn = 0; xn < 2; ++xn)
                        acc[cm][xn] = __builtin_amdgcn_mfma_f32_32x32x16_f16(
                            afr[cm], bfr[xn], acc[cm][xn], 0, 0, 0);
                __builtin_amdgcn_s_setprio(0);
            }

            __syncthreads();
            cur ^= 1;
        }

        // insert this tile's values into per-lane top-2.
        // C/D layout (32x32): col(=x-row)=l&31, code row=(r&3)+8*(r>>2)+4*kg
#pragma unroll
        for (int xn = 0; xn < 2; ++xn) {
#pragma unroll
            for (int cm = 0; cm < 4; ++cm) {
                const int cbase = ct * CT + wc * 128 + cm * 32 + 4 * kg;
#pragma unroll
                for (int r = 0; r < 16; ++r) {
                    float v = acc[cm][xn][r];
                    int  cc = cbase + (r & 3) + 8 * (r >> 2);
                    bool b0 = v > q0[xn];
                    bool b1 = v > q1[xn];
                    q1[xn] = b1 ? (b0 ? q0[xn] : v)  : q1[xn];
                    i1[xn] = b1 ? (b0 ? i0[xn] : cc) : i1[xn];
                    q0[xn] = b0 ? v  : q0[xn];
                    i0[xn] = b0 ? cc : i0[xn];
                }
            }
        }
    }

    // merge: 16 candidates/row via LDS -> exact top-4 -> cand[]
    __syncthreads();
    float2* cl = (float2*)lds;            // [128 rows][16 slots]
#pragma unroll
    for (int xn = 0; xn < 2; ++xn) {
        int rl = wr * 64 + xn * 32 + lm;
        cl[rl * 16 + wc * 4 + kg * 2 + 0] = make_float2(q0[xn], __int_as_float(i0[xn]));
        cl[rl * 16 + wc * 4 + kg * 2 + 1] = make_float2(q1[xn], __int_as_float(i1[xn]));
    }
    __syncthreads();

    if (tid < RB) {
        float t0 = -3.0e38f, t1 = -3.0e38f, t2 = -3.0e38f, t3 = -3.0e38f;
        int   u0 = 0, u1 = 0, u2 = 0, u3 = 0;
        for (int k = 0; k < 16; ++k) {
            float2 p = cl[tid * 16 + k];
            float v = p.x; int cc = __float_as_int(p.y);
            bool b0 = v > t0, b1 = v > t1, b2 = v > t2, b3 = v > t3;
            t3 = b3 ? (b2 ? t2 : v)  : t3;  u3 = b3 ? (b2 ? u2 : cc) : u3;
            t2 = b2 ? (b1 ? t1 : v)  : t2;  u2 = b2 ? (b1 ? u1 : cc) : u2;
            t1 = b1 ? (b0 ? t0 : v)  : t1;  u1 = b1 ? (b0 ? u0 : cc) : u1;
            t0 = b0 ? v : t0;               u0 = b0 ? cc : u0;
        }
        int4 w; w.x = u0; w.y = u1; w.z = u2; w.w = u3;
        *(int4*)(cand + (row0 + tid) * 4) = w;
    }
}

// exact fp32 rerank of the 4 candidates + gather e[winner] -> out
__global__ __launch_bounds__(256)
void rerank_gather(const float* __restrict__ x, const float* __restrict__ e,
                   const int* __restrict__ cand, float* __restrict__ out) {
    const int tid = threadIdx.x;
    const int l   = tid & 63;
    const int w   = tid >> 6;
    const long row = (long)blockIdx.x * 4 + w;

    const float* xr = x + row * K_DIM + l * 8;
    f32x4 xv0 = *(const f32x4*)(xr);
    f32x4 xv1 = *(const f32x4*)(xr + 4);

    float d[4]; int c[4];
#pragma unroll
    for (int i = 0; i < 4; ++i) {
        c[i] = cand[row * 4 + i];
        const float* er = e + (long)c[i] * K_DIM + l * 8;
        f32x4 ev0 = *(const f32x4*)(er);
        f32x4 ev1 = *(const f32x4*)(er + 4);
        float s = 0.0f;
        s = fmaf(xv0[0], ev0[0], s); s = fmaf(xv0[1], ev0[1], s);
        s = fmaf(xv0[2], ev0[2], s); s = fmaf(xv0[3], ev0[3], s);
        s = fmaf(xv1[0], ev1[0], s); s = fmaf(xv1[1], ev1[1], s);
        s = fmaf(xv1[2], ev1[2], s); s = fmaf(xv1[3], ev1[3], s);
        d[i] = s;
    }
#pragma unroll
    for (int m = 1; m < 64; m <<= 1)
#pragma unroll
        for (int i = 0; i < 4; ++i) d[i] += __shfl_xor(d[i], m);

    float bv = d[0]; int bc = c[0];
#pragma unroll
    for (int i = 1; i < 4; ++i)
        if (d[i] > bv || (d[i] == bv && c[i] < bc)) { bv = d[i]; bc = c[i]; }

    const float4* src = (const float4*)(e + (long)bc * K_DIM) + l * 2;
    float4*       dst = (float4*)(out + row * K_DIM) + l * 2;
    dst[0] = src[0];
    dst[1] = src[1];
}

extern "C" void kernel_launch(void* const* d_in, const int* in_sizes, int n_in,
                              void* d_out, int out_size, void* d_ws, size_t ws_size,
                              hipStream_t stream) {
    const float* x = (const float*)d_in[0];   // [M, 512] fp32
    const float* e = (const float*)d_in[1];   // [4096, 512] fp32
    float* out = (float*)d_out;

    const int M  = in_sizes[0] / K_DIM;       // 32768
    const int Ce = in_sizes[1] / K_DIM;       // 4096

    _Float16* X1 = (_Float16*)d_out;                                   // 32 MiB, dead before out written
    _Float16* E1 = (_Float16*)d_ws;                                    // 4 MiB
    int* cand    = (int*)((char*)d_ws + (size_t)Ce * K_DIM * 2);       // M*4 ints

    (void)hipFuncSetAttribute((const void*)vq_gemm,
                              hipFuncAttributeMaxDynamicSharedMemorySize, 163840);

    const int xb = M / 4, eb = Ce / 4;
    convert_f16<<<xb + eb, 256, 0, stream>>>(x, e, X1, E1, xb);
    vq_gemm<<<M / RB, 512, 163840, stream>>>(X1, E1, cand);
    rerank_gather<<<M / 4, 256, 0, stream>>>(x, e, cand, out);
}